// Round 19
// baseline (176.548 us; speedup 1.0000x reference)
//
#include <hip/hip_runtime.h>
#include <cstddef>
#include <cstdint>

// B=4, S=1024, D=512, H=8, DK=64, DFF=512, M=4096. SCALE=0.125.
// Fixed-max softmax (scores ~ +-2): associative exp-sum, no online-max.
// Q projections pre-scaled by 0.125*log2(e) => v_exp_f32 (2^x) per score.
// r19: attn_enc ported to the r18-dual k-split structure (4 q-waves x 2
// k-halves, KVBLK=32, 40 KB LDS) + __launch_bounds__(512,8) to pin VGPR
// into the <=64 band -> 4 blocks/CU = 32 waves/CU (was 16, VGPR-capped).
// Everything else = r18 (wide G1, n64 3-buf, k-split dual, setprio).

typedef __attribute__((ext_vector_type(8))) short s8v;   // 8 x bf16
typedef __attribute__((ext_vector_type(4))) short s4v;   // 4 x bf16
typedef __attribute__((ext_vector_type(4))) float f4v;   // MFMA acc

#define QSC 0.1803368801111444f   // 0.125 * log2(e)
#define EXP2(x) __builtin_amdgcn_exp2f(x)
#define WAITV(N) asm volatile("s_waitcnt vmcnt(" #N ")" ::: "memory")
#define BAR() __builtin_amdgcn_s_barrier()
#define PRIO(n) __builtin_amdgcn_s_setprio(n)

static __device__ __forceinline__ short f2bf(float f){
  unsigned int u = __builtin_bit_cast(unsigned int, f);
  u += 0x7fffu + ((u >> 16) & 1u);          // RNE
  return (short)(u >> 16);
}
static __device__ __forceinline__ float bf2f(short s){
  unsigned int u = ((unsigned int)(unsigned short)s) << 16;
  return __builtin_bit_cast(float, u);
}
static __device__ __forceinline__ void gload16(const void* g, void* l){
  __builtin_amdgcn_global_load_lds(
      (const __attribute__((address_space(1))) unsigned int*)g,
      (__attribute__((address_space(3))) unsigned int*)l, 16, 0, 0);
}
#define MFMA16(a,b,c) __builtin_amdgcn_mfma_f32_16x16x32_bf16(a,b,c,0,0,0)

// ---------------------------------------------------------------------------
// Fused input-convert + weight-pack.
// ---------------------------------------------------------------------------
struct Ptr19 { const float* p[19]; };

__global__ __launch_bounds__(256) void prep(const float* __restrict__ a,
                                            const float* __restrict__ v,
                                            short* __restrict__ oa,
                                            short* __restrict__ ov,
                                            Ptr19 ws, short* __restrict__ wp){
  const int b = blockIdx.x, tid = threadIdx.x;
  if (b < 2048){
    const float* src = (b >= 1024) ? v : a;
    short* dst = (b >= 1024) ? ov : oa;
    const int i = ((b & 1023) * 256 + tid) * 8;
    float4 x = *reinterpret_cast<const float4*>(src + i);
    float4 y = *reinterpret_cast<const float4*>(src + i + 4);
    s8v o;
    o[0]=f2bf(x.x); o[1]=f2bf(x.y); o[2]=f2bf(x.z); o[3]=f2bf(x.w);
    o[4]=f2bf(y.x); o[5]=f2bf(y.y); o[6]=f2bf(y.z); o[7]=f2bf(y.w);
    *reinterpret_cast<s8v*>(dst + i) = o;
  } else {
    const int pb = b - 2048;
    const int mat = pb >> 7;
    const float* W = ws.p[mat];
    const int f = (pb & 127) * 256 + tid;   // 0..32767
    const int nblk = f >> 10, kg = (f >> 4) & 63, nl = f & 15;
    const int n = nblk * 16 + nl, k = kg * 8;
    s8v o;
#pragma unroll
    for (int e = 0; e < 8; ++e) o[e] = f2bf(W[(size_t)(k + e) * 512 + n]);
    *reinterpret_cast<s8v*>(wp + (size_t)mat * 262144 + (size_t)f * 8) = o;
  }
}

// ---------------------------------------------------------------------------
// G1 GEMM: 128x256 tile, 4 waves x (64x128), acc[4][8]. 3-buffer, 1 barrier
// per K-step, vmcnt(6). mode: 0 plain, 1 QSC, 2 packed-V.
// ---------------------------------------------------------------------------
struct GemmJobs { const short* A[12]; const short* W[12]; const float* bias[12];
                  short* C[12]; int mode[12]; };

__global__ __launch_bounds__(256, 2) void gemm_wide(GemmJobs J){
  int i = (blockIdx.z * 32 + blockIdx.y) * 2 + blockIdx.x;
  const int c = (64 * gridDim.z) >> 3;
  i = (i & 7) * c + (i >> 3);
  const int z = i >> 6, rem = i & 63;
  const int by = rem >> 1, bx = rem & 1;

  const short* __restrict__ A = J.A[z];
  const short* __restrict__ Wp = J.W[z];
  const float* __restrict__ bias = J.bias[z];
  short* __restrict__ C = J.C[z];
  const int md = J.mode[z];
  __shared__ short smem[36864];                 // 72 KB arena
  const int tid = threadIdx.x, lane = tid & 63, w = tid >> 6;
  const int wm = w >> 1, wn = w & 1;
  const int m0 = by * 128, n0 = bx * 256;
  const int lh = lane >> 4, ll = lane & 15;
  f4v acc[4][8] = {};

  auto stage = [&](int kt, int buf){
    const int k0 = kt * 32;
    short* As = smem + buf * 4096;
    short* Bs = smem + 12288 + buf * 8192;
#pragma unroll
    for (int p = 0; p < 2; ++p){
      const int f = tid + 256 * p;
      const int blk = f >> 6, kg = (f >> 4) & 3, il = f & 15;
      gload16(A + (size_t)(m0 + blk * 16 + il) * 512 + k0 + kg * 8, As + f * 8);
    }
#pragma unroll
    for (int p = 0; p < 4; ++p){
      const int f = tid + 256 * p;
      const int cblk = f >> 6, kg = (f >> 4) & 3, il = f & 15;
      gload16(Wp + ((size_t)(((n0 >> 4) + cblk) * 64 + (k0 >> 3) + kg) * 16 + il) * 8,
              Bs + f * 8);
    }
  };

  stage(0, 0);
  stage(1, 1);
#pragma unroll 1
  for (int kt = 0; kt < 16; ++kt){
    if (kt < 15) { WAITV(6); } else { WAITV(0); }
    BAR();
    if (kt < 14) stage(kt + 2, (kt + 2) % 3);
    const int cur = kt % 3;
    const short* As = smem + cur * 4096;
    const short* Bs = smem + 12288 + cur * 8192;
    s8v a[4], b[8];
#pragma unroll
    for (int q = 0; q < 4; ++q)
      a[q] = *reinterpret_cast<const s8v*>(&As[(((wm*4+q)*4 + lh)*16 + ll) * 8]);
#pragma unroll
    for (int j = 0; j < 8; ++j)
      b[j] = *reinterpret_cast<const s8v*>(&Bs[(((wn*8+j)*4 + lh)*16 + ll) * 8]);
    PRIO(1);
#pragma unroll
    for (int q = 0; q < 4; ++q)
#pragma unroll
      for (int j = 0; j < 8; ++j)
        acc[q][j] = MFMA16(a[q], b[j], acc[q][j]);
    PRIO(0);
  }
  BAR();                          // epilogue reuses arena

  if (md == 2){
#pragma unroll
    for (int j = 0; j < 8; ++j){
      const int col = n0 + wn * 128 + j * 16 + ll;
      const float bv = bias[col];
      const int hh = col >> 6, dl = col & 63, dblk = dl >> 4, il = dl & 15;
#pragma unroll
      for (int q = 0; q < 4; ++q){
        const int rowb = m0 + wm * 64 + q * 16 + lh * 4;
        const int bb = rowb >> 10, srow = rowb & 1023;
        const size_t off = ((size_t)((bb*8 + hh)*16 + (srow >> 6))) * 4096
                         + (size_t)(((dblk << 7) + (((srow >> 3) & 7) << 4) + il) * 8 + (srow & 7));
        s4v o4;
#pragma unroll
        for (int r = 0; r < 4; ++r) o4[r] = f2bf(acc[q][j][r] + bv);
        *reinterpret_cast<s4v*>(&C[off]) = o4;
      }
    }
  } else {
    short* epi = smem + w * 8192;
    const float sc = (md == 1) ? QSC : 1.0f;
#pragma unroll
    for (int j = 0; j < 8; ++j){
      const float bv = bias[n0 + wn * 128 + j * 16 + ll];
#pragma unroll
      for (int q = 0; q < 4; ++q)
#pragma unroll
        for (int r = 0; r < 4; ++r)
          epi[(q*16 + lh*4 + r)*128 + j*16 + ll] = f2bf((acc[q][j][r] + bv) * sc);
    }
#pragma unroll
    for (int i2 = 0; i2 < 16; ++i2){
      const int row = i2 * 4 + (lane >> 4);
      s8v vr = *reinterpret_cast<const s8v*>(&epi[row*128 + (lane & 15)*8]);
      *reinterpret_cast<s8v*>(&C[(size_t)(m0 + wm*64 + row)*512 + n0 + wn*128 + (lane&15)*8]) = vr;
    }
  }
}

// ---------------------------------------------------------------------------
// bf16 MFMA GEMM, 128x64 tile (small launches). 3-buffer, 1 barrier/K-step.
// ---------------------------------------------------------------------------
template<bool RELU>
__global__ __launch_bounds__(256) void gemm_n64(GemmJobs J){
  int i = (blockIdx.z * 32 + blockIdx.y) * 8 + blockIdx.x;
  const int c = (256 * gridDim.z) >> 3;
  i = (i & 7) * c + (i >> 3);
  const int z = i >> 8, rem = i & 255;
  const int by = rem >> 3, bx = rem & 7;

  const short* __restrict__ A = J.A[z];
  const short* __restrict__ Wp = J.W[z];
  const float* __restrict__ bias = J.bias[z];
  short* __restrict__ C = J.C[z];
  __shared__ short As[3][4096], Bs[3][2048];   // 36 KB
  const int tid = threadIdx.x, lane = tid & 63, w = tid >> 6;
  const int wm = w >> 1, wn = w & 1;
  const int m0 = by * 128, n0 = bx * 64;
  const int lh = lane >> 4, ll = lane & 15;
  f4v acc[4][2] = {};

  auto stage = [&](int kt, int buf){
    const int k0 = kt * 32;
#pragma unroll
    for (int p = 0; p < 2; ++p){
      const int f = tid + 256 * p;
      const int blk = f >> 6, kg = (f >> 4) & 3, il = f & 15;
      gload16(A + (size_t)(m0 + blk * 16 + il) * 512 + k0 + kg * 8, &As[buf][f * 8]);
    }
    {
      const int f = tid;
      const int blk = f >> 6, kg = (f >> 4) & 3, il = f & 15;
      gload16(Wp + ((size_t)(((n0 >> 4) + blk) * 64 + (k0 >> 3) + kg) * 16 + il) * 8,
              &Bs[buf][f * 8]);
    }
  };

  stage(0, 0);
  stage(1, 1);
#pragma unroll 1
  for (int kt = 0; kt < 16; ++kt){
    if (kt < 15) { WAITV(3); } else { WAITV(0); }
    BAR();
    if (kt < 14) stage(kt + 2, (kt + 2) % 3);
    const int cur = kt % 3;
    s8v a[4], b[2];
#pragma unroll
    for (int q = 0; q < 4; ++q)
      a[q] = *reinterpret_cast<const s8v*>(&As[cur][(((wm*4+q)*4 + lh)*16 + ll) * 8]);
#pragma unroll
    for (int j = 0; j < 2; ++j)
      b[j] = *reinterpret_cast<const s8v*>(&Bs[cur][(((wn*2+j)*4 + lh)*16 + ll) * 8]);
    PRIO(1);
#pragma unroll
    for (int q = 0; q < 4; ++q)
#pragma unroll
      for (int j = 0; j < 2; ++j)
        acc[q][j] = MFMA16(a[q], b[j], acc[q][j]);
    PRIO(0);
  }
  BAR();

  short* epi = &As[0][0] + w * 2048;
#pragma unroll
  for (int j = 0; j < 2; ++j){
    const float bv = bias[n0 + wn * 32 + j * 16 + ll];
#pragma unroll
    for (int q = 0; q < 4; ++q)
#pragma unroll
      for (int r = 0; r < 4; ++r){
        float v = acc[q][j][r] + bv;
        if (RELU) v = fmaxf(v, 0.f);
        epi[(q*16 + lh*4 + r)*32 + j*16 + ll] = f2bf(v);
      }
  }
#pragma unroll
  for (int i2 = 0; i2 < 4; ++i2){
    const int row = i2 * 16 + (lane >> 2);
    s8v vr = *reinterpret_cast<const s8v*>(&epi[row*32 + (lane & 3)*8]);
    *reinterpret_cast<s8v*>(&C[(size_t)(m0 + wm*64 + row)*512 + n0 + wn*32 + (lane&3)*8]) = vr;
  }
}

// ---------------------------------------------------------------------------
// Encoder self-attention, swapped QK^T, k-split. 8 waves = 4 q-waves (16 q
// each, 64 q/block) x 2 k-halves; KVBLK=32; each wave stages its own half.
// 1024 blocks, 40 KB LDS, launch_bounds(512,8) -> target 4 blocks/CU.
// LDS (shorts): K@0 [hh*4096+buf*2048], V@8192 same, PL@16384 (8x512).
// ---------------------------------------------------------------------------
struct AttnJob { const short* Q; const short* K; const short* Vp; short* O; };

__global__ __launch_bounds__(512, 8) void attn_enc(AttnJob j0, AttnJob j1){
  const AttnJob jb = blockIdx.z ? j1 : j0;
  __shared__ short smem[20480];                // 40 KB
  const int tid = threadIdx.x, lane = tid & 63, w = tid >> 6;
  const int qw = w & 3, kh = w >> 2;
  int bi = blockIdx.y * 16 + blockIdx.x;       // 512 blocks per job
  bi = (bi & 7) * 64 + (bi >> 3);              // bijective XCD swizzle
  const int qt = bi & 15, bh = bi >> 4;
  const int b = bh >> 3, h = bh & 7;
  const int q0 = qt * 64;
  const size_t base = (size_t)b * 1024 * 512 + (size_t)h * 64;
  const int lh = lane >> 4, ll = lane & 15;
  short* PLw = smem + 16384 + w * 512;

  s8v qf[2];
#pragma unroll
  for (int df = 0; df < 2; ++df)
    qf[df] = *reinterpret_cast<const s8v*>(jb.Q + base + (size_t)(q0 + qw*16 + ll)*512 + lh*8 + df*32);

  const int hh = tid >> 8;                     // == kh
  const int u = tid & 255;
  const int kblk = u >> 7, kg8 = (u >> 4) & 7, kil = u & 15;
  const int vdb = u >> 6, vk4 = (u >> 4) & 3,  vil = u & 15;

  auto stage = [&](int it, int buf){
    const int dso = hh * 4096 + buf * 2048 + u * 8;
    gload16(jb.K + base + (size_t)(hh*512 + it*32 + kblk*16 + kil)*512 + kg8*8, smem + dso);
    const int kt16 = hh*8 + (it >> 1);
    const int kgrp = (it & 1)*4 + vk4;
    gload16(jb.Vp + ((size_t)bh*16 + kt16)*4096 + (size_t)((vdb*8 + kgrp)*16 + vil)*8,
            smem + 8192 + dso);
  };

  f4v o[4] = {};
  float zacc = 0.f;
  const int pwo = ((lh >> 1) * 16 + ll) * 8 + (lh & 1) * 4;   // P^T write
  const int pro = (lh * 16 + ll) * 8;                         // P^T read

  stage(0, 0);
#pragma unroll 1
  for (int it = 0; it < 16; ++it){
    if (it < 15) { stage(it + 1, (it + 1) & 1); WAITV(2); }
    else         { WAITV(0); }
    BAR();
    const int to = kh * 4096 + (it & 1) * 2048;
    const short* pK = smem + to;
    const short* pV = smem + 8192 + to;

    f4v s[2] = {};
    PRIO(1);
#pragma unroll
    for (int fn = 0; fn < 2; ++fn)
#pragma unroll
      for (int df = 0; df < 2; ++df){
        s8v kf = *reinterpret_cast<const s8v*>(&pK[(fn*128 + (lh + df*4)*16 + ll) * 8]);
        s[fn] = MFMA16(kf, qf[df], s[fn]);    // P^T: row=k, col=q
      }
    PRIO(0);

#pragma unroll
    for (int fn = 0; fn < 2; ++fn){
      s4v p4;
#pragma unroll
      for (int r = 0; r < 4; ++r){
        const float p = EXP2(s[fn][r]);
        zacc += p;
        p4[r] = f2bf(p);
      }
      *reinterpret_cast<s4v*>(&PLw[fn*256 + pwo]) = p4;
    }
    s8v pa = *reinterpret_cast<const s8v*>(&PLw[pro]);
    PRIO(1);
#pragma unroll
    for (int fd = 0; fd < 4; ++fd){
      s8v vf = *reinterpret_cast<const s8v*>(&pV[(fd*64 + lh*16 + ll) * 8]);
      o[fd] = MFMA16(vf, pa, o[fd]);          // O^T: row=d, col=q
    }
    PRIO(0);
    BAR();
  }

  // combine k-halves via LDS float area (17 KB)
  float* cb = (float*)smem;
  const int idx = qw * 64 + lane;
  if (kh == 1){
#pragma unroll
    for (int fd = 0; fd < 4; ++fd)
#pragma unroll
      for (int r = 0; r < 4; ++r) cb[(fd*4 + r)*256 + idx] = o[fd][r];
    cb[16*256 + idx] = zacc;
  }
  BAR();
  if (kh == 0){
#pragma unroll
    for (int fd = 0; fd < 4; ++fd)
#pragma unroll
      for (int r = 0; r < 4; ++r) o[fd][r] += cb[(fd*4 + r)*256 + idx];
    float Z = zacc + cb[16*256 + idx];
    Z += __shfl_xor(Z, 16); Z += __shfl_xor(Z, 32);
    const float rz = 1.f / Z;
#pragma unroll
    for (int fd = 0; fd < 4; ++fd){
      s4v o4;
#pragma unroll
      for (int r = 0; r < 4; ++r) o4[r] = f2bf(o[fd][r] * rz);
      *reinterpret_cast<s4v*>(&jb.O[base + (size_t)(q0 + qw*16 + ll)*512 + fd*16 + lh*4]) = o4;
    }
  }
}

// ---------------------------------------------------------------------------
// Dual-softmax cross attention, swapped QK^T, k-split (r18, unchanged).
// ---------------------------------------------------------------------------
__global__ __launch_bounds__(512) void attn_dual(const short* __restrict__ Qa, const short* __restrict__ Ka,
                                                 const short* __restrict__ Vap, const short* __restrict__ Qv,
                                                 const short* __restrict__ Kv, const short* __restrict__ Vvp,
                                                 short* __restrict__ O){
  __shared__ short smem[36864];                // 72 KB
  const int tid = threadIdx.x, lane = tid & 63, w = tid >> 6;
  const int qw = w & 3, kh = w >> 2;
  int bi = blockIdx.y * 16 + blockIdx.x;       // 512 blocks
  bi = (bi & 7) * 64 + (bi >> 3);
  const int qt = bi & 15, bh = bi >> 4;
  const int b = bh >> 3, h = bh & 7;
  const int q0 = qt * 64;
  const size_t base = (size_t)b * 1024 * 512 + (size_t)h * 64;
  const int lh = lane >> 4, ll = lane & 15;
  short* PLw = smem + 32768 + w * 512;

  s8v qfa[2], qfv[2];
#pragma unroll
  for (int df = 0; df < 2; ++df){
    const size_t ro = base + (size_t)(q0 + qw*16 + ll)*512 + lh*8 + df*32;
    qfa[df] = *reinterpret_cast<const s8v*>(Qa + ro);
    qfv[df] = *reinterpret_cast<const s8v*>(Qv + ro);
  }

  const int hh = tid >> 8;
  const int u = tid & 255;
  const int kblk = u >> 7, kg8 = (u >> 4) & 7, kil = u & 15;
  const int vdb = u >> 6, vk4 = (u >> 4) & 3,  vil = u & 15;

  auto stage = [&](int it, int buf){
    const int dso = hh * 4096 + buf * 2048 + u * 8;
    const size_t krow = base + (size_t)(hh*512 + it*32 + kblk*16 + kil)*512 + kg8*8;
    gload16(Ka + krow, smem + dso);
    gload16(Kv + krow, smem + 8192 + dso);
    const int kt16 = hh*8 + (it >> 1);
    const int kgrp = (it & 1)*4 + vk4;
    const size_t voff = ((size_t)bh*16 + kt16)*4096 + (size_t)((vdb*8 + kgrp)*16 + vil)*8;
    gload16(Vap + voff, smem + 16384 + dso);
    gload16(Vvp + voff, smem + 24576 + dso);
  };

  f4v oa[4] = {}, ov[4] = {};
  float za = 0.f, zv = 0.f;
  const int pwo = ((lh >> 1) * 16 + ll) * 8 + (lh & 1) * 4;
  const int pro = (lh * 16 + ll) * 8;

  stage(0, 0);
#pragma unroll 1
  for (int it = 0; it < 16; ++it){
    if (it < 15) { stage(it + 1, (it + 1) & 1); WAITV(4); }
    else         { WAITV(0); }
    BAR();
    const int cur = it & 1;
    const int to = kh * 4096 + cur * 2048;
    const short* pKa = smem + to;
    const short* pKv = smem + 8192 + to;
    const short* pVa = smem + 16384 + to;
    const short* pVv = smem + 24576 + to;

    f4v sa[2] = {}, sv[2] = {};
    PRIO(1);
#pragma unroll
    for (int fn = 0; fn < 2; ++fn)
#pragma unroll
      for (int df = 0; df < 2; ++df){
        const int boff = (fn*128 + (lh + df*4)*16 + ll) * 8;
        s8v ka = *reinterpret_cast<const s8v*>(&pKa[boff]);
        s8v kv = *reinterpret_cast<const s8v*>(&pKv[boff]);
        sa[fn] = MFMA16(ka, qfa[df], sa[fn]);
        sv[fn] = MFMA16(kv, qfv[df], sv[fn]);
      }
    PRIO(0);

#pragma unroll
    for (int fn = 0; fn < 2; ++fn){
      s4v p4;
#pragma unroll
      for (int r = 0; r < 4; ++r){
        const float ea = EXP2(sa[fn][r]);
        const float ev = EXP2(sv[fn][r]);
        za += ea; zv += ev;
        p4[r] = f2bf(ea * ev);
      }
      *reinterpret_cast<s4v*>(&PLw[fn*256 + pwo]) = p4;
    }
    s8v pa = *reinterpret_cast<const s8v*>(&PLw[pro]);
    PRIO(1);
#pragma unroll
    for (int fd = 0; fd < 4; ++fd){
      const int voff2 = (fd*64 + lh*16 + ll) * 8;
      s8v va = *reinterpret_cast<const s8v*>(&pVa[voff2]);
      s8v vv = *reinterpret_cast<const s8v*>(&pVv[voff2]);
      oa[fd] = MFMA16(va, pa, oa[fd]);
      ov[fd] = MFMA16(vv, pa, ov[fd]);
    }
    PRIO(0);
    BAR();
  }

  float* cb = (float*)smem;                    // 34 KB combine area
  const int idx = qw * 64 + lane;
  if (kh == 1){
#pragma unroll
    for (int fd = 0; fd < 4; ++fd)
#pragma unroll
      for (int r = 0; r < 4; ++r){
        cb[(fd*4 + r)*256 + idx] = oa[fd][r];
        cb[(16 + fd*4 + r)*256 + idx] = ov[fd][r];
      }
    cb[32*256 + idx] = za;
    cb[33*256 + idx] = zv;
  }
  BAR();
  if (kh == 0){
#pragma unroll
    for (int fd = 0; fd < 4; ++fd)
#pragma unroll
      for (int r = 0; r < 4; ++r){
        oa[fd][r] += cb[(fd*4 + r)*256 + idx];
        ov[fd][r] += cb[(16 + fd*4 + r)*256 + idx];
      }
    float Za = za + cb[32*256 + idx];
    float Zv = zv + cb[33*256 + idx];
    Za += __shfl_xor(Za, 16); Za += __shfl_xor(Za, 32);
    Zv += __shfl_xor(Zv, 16); Zv += __shfl_xor(Zv, 32);
    const float rz = 1.f / (Za * Zv);
#pragma unroll
    for (int fd = 0; fd < 4; ++fd){
      s4v o4;
#pragma unroll
      for (int r = 0; r < 4; ++r){
        const float v = (oa[fd][r] * rz) * (ov[fd][r] * rz);
        o4[r] = f2bf(v);
      }
      *reinterpret_cast<s4v*>(&O[base + (size_t)(q0 + qw*16 + ll)*512 + fd*16 + lh*4]) = o4;
    }
  }
}

// ---------------------------------------------------------------------------
struct LnJob { const short* xb0; const short* xb1; const short* xb2;
               const float* xf; const float* g; const float* bb; void* out; };

template<int NBF, bool ADDF32, bool OUTF32>
__global__ __launch_bounds__(256) void ln_fused(LnJob j0, LnJob j1){
  const LnJob j = blockIdx.y ? j1 : j0;
  const int row = blockIdx.x, t = threadIdx.x;
  const size_t base = (size_t)row * 512;
  float x[2];
#pragma unroll
  for (int u = 0; u < 2; ++u){
    const int c = t + u * 256;
    float v = bf2f(j.xb0[base + c]);
    if (NBF > 1) v += bf2f(j.xb1[base + c]);
    if (NBF > 2) v += bf2f(j.xb2[base + c]);
    if (ADDF32) v += j.xf[base + c];
    x[u] = v;
  }
  float s = x[0] + x[1], ss = x[0]*x[0] + x[1]*x[1];
#pragma unroll
  for (int o = 32; o; o >>= 1){ s += __shfl_xor(s, o); ss += __shfl_xor(ss, o); }
  __shared__ float rb[8];
  const int wv = t >> 6;
  if ((t & 63) == 0){ rb[wv] = s; rb[wv + 4] = ss; }
  __syncthreads();
  s  = rb[0] + rb[1] + rb[2] + rb[3];
  ss = rb[4] + rb[5] + rb[6] + rb[7];
  const float m = s * (1.f / 512.f);
  const float var = ss * (1.f / 512.f) - m * m;
  const float rstd = rsqrtf(var + 1e-5f);
#pragma unroll
  for (int u = 0; u < 2; ++u){
    const int c = t + u * 256;
    const float v = (x[u] - m) * rstd * j.g[c] + j.bb[c];
    if (OUTF32) ((float*)j.out)[base + c] = v;
    else        ((short*)j.out)[base + c] = f2bf(v);
  }
}

// ---------------------------------------------------------------------------
// Fused LN2(audio) + LN2(video) + final LN.
// ---------------------------------------------------------------------------
__global__ __launch_bounds__(256) void ln_final(const short* __restrict__ fa, const short* __restrict__ ha,
                                                const short* __restrict__ fv, const short* __restrict__ hv,
                                                const short* __restrict__ ctx, const float* __restrict__ audio,
                                                const float* __restrict__ g2a, const float* __restrict__ b2a,
                                                const float* __restrict__ g2v, const float* __restrict__ b2v,
                                                const float* __restrict__ gf, const float* __restrict__ bf,
                                                float* __restrict__ out){
  const int row = blockIdx.x, t = threadIdx.x;
  const size_t base = (size_t)row * 512;
  __shared__ float rb[24];
  const int wv = t >> 6;

  auto reduce2 = [&](float a, float b, int p){
    float s = a + b, ss = a*a + b*b;
#pragma unroll
    for (int o = 32; o; o >>= 1){ s += __shfl_xor(s, o); ss += __shfl_xor(ss, o); }
    if ((t & 63) == 0){ rb[p*8 + wv] = s; rb[p*8 + 4 + wv] = ss; }
  };
  auto stats = [&](int p, float& m, float& rstd){
    const float s  = rb[p*8+0] + rb[p*8+1] + rb[p*8+2] + rb[p*8+3];
    const float ss = rb[p*8+4] + rb[p*8+5] + rb[p*8+6] + rb[p*8+7];
    m = s * (1.f / 512.f);
    rstd = rsqrtf(ss * (1.f / 512.f) - m * m + 1e-5f);
  };

  float xa[2], xv[2];
#pragma unroll
  for (int u = 0; u < 2; ++u){
    const int c = t + u * 256;
    xa[u] = bf2f(fa[base + c]) + bf2f(ha[base + c]);
    xv[u] = bf2f(fv[base + c]) + bf2f(hv[base + c]);
  }
  reduce2(xa[0], xa[1], 0);
  reduce2(xv[0], xv[1], 1);
  __syncthreads();
  float ma, ra, mv, rv;
  stats(0, ma, ra);
  stats(1, mv, rv);

  float xf[2];
#pragma unroll
  for (int u = 0; u < 2; ++u){
    const int c = t + u * 256;
    const float sa = (xa[u] - ma) * ra * g2a[c] + b2a[c];
    const float sv = (xv[u] - mv) * rv * g2v[c] + b2v[c];
    xf[u] = audio[base + c] + bf2f(ctx[base + c]) + sa + sv;
  }
  reduce2(xf[0], xf[1], 2);
  __syncthreads();
  float mf, rf;
  stats(2, mf, rf);
#pragma unroll
  for (int u = 0; u < 2; ++u){
    const int c = t + u * 256;
    out[base + c] = (xf[u] - mf) * rf * gf[c] + bf[c];
  }
}

// ---------------------------------------------------------------------------
extern "C" void kernel_launch(void* const* d_in, const int* in_sizes, int n_in,
                              void* d_out, int out_size, void* d_ws, size_t ws_size,
                              hipStream_t stream) {
  const float* audio = (const float*)d_in[0];
  const float* video = (const float*)d_in[1];
  auto F = [&](int i){ return (const float*)d_in[i]; };

  short* ws16 = (short*)d_ws;
  const size_t SL = 2097152;                       // shorts per 4MB slot
  auto S = [&](int i){ return ws16 + (size_t)i * SL; };
  short* Wp = S(12);                               // 19 * 262144 shorts
  auto WP = [&](int i){ return (const short*)(Wp + (size_t)i * 262144); };
  short* Kcv = (short*)d_out;                      // d_out as bf16 scratch
  short* Vcv = (short*)d_out + SL;

  // 1. fused: inputs -> bf16 + pack 19 weights
  Ptr19 pw;
  const int widx[19] = {18,19,20,21,26,28, 34,35,36,37,42,44, 2,4,6,8,10,12, 14};
  for (int i = 0; i < 19; ++i) pw.p[i] = F(widx[i]);
  prep<<<4480, 256, 0, stream>>>(audio, video, S(10), S(11), pw, Wp);

  // 2. G1: all 12 QKV projections (wide tile); Q scaled, V packed
  GemmJobs g1{};
  const short* g1A[12] = {S(10),S(10),S(10), S(11),S(11),S(11), S(10),S(10),S(10), S(11),S(11),S(11)};
  const short* g1W[12] = {WP(0),WP(1),WP(2), WP(6),WP(7),WP(8), WP(12),WP(13),WP(14), WP(15),WP(16),WP(17)};
  const float* g1B[12] = {F(22),F(23),F(24), F(38),F(39),F(40), F(3),F(5),F(7), F(9),F(11),F(13)};
  short*       g1C[12] = {S(0),S(1),S(2), S(3),S(4),S(5), S(6),S(7),S(8), S(9),Kcv,Vcv};
  const int    g1M[12] = {1,0,2, 1,0,2, 1,0,2, 1,0,2};
  for (int i = 0; i < 12; ++i){ g1.A[i]=g1A[i]; g1.W[i]=g1W[i]; g1.bias[i]=g1B[i]; g1.C[i]=g1C[i]; g1.mode[i]=g1M[i]; }
  gemm_wide<<<dim3(2,32,12), 256, 0, stream>>>(g1);

  // 3. encoder self-attention (k-split, 1024 blocks): ctx -> S(10), S(11)
  attn_enc<<<dim3(16,32,2), 512, 0, stream>>>(AttnJob{S(0),S(1),S(2),S(10)},
                                              AttnJob{S(3),S(4),S(5),S(11)});

  // 4. dual cross-attention (k-split, 512 blocks) -> S(0)
  attn_dual<<<dim3(16,32), 512, 0, stream>>>(S(6),S(7),S(8), S(9),Kcv,Vcv, S(0));

  // 5. G3+G9 merged: ctxA@ow->S(1), ctxV@ow->S(2), ctxD@out_w->S(3)
  GemmJobs g39{};
  g39.A[0]=S(10); g39.W[0]=WP(3);  g39.bias[0]=F(25); g39.C[0]=S(1); g39.mode[0]=0;
  g39.A[1]=S(11); g39.W[1]=WP(9);  g39.bias[1]=F(41); g39.C[1]=S(2); g39.mode[1]=0;
  g39.A[2]=S(0);  g39.W[2]=WP(18); g39.bias[2]=F(15); g39.C[2]=S(3); g39.mode[2]=0;
  gemm_n64<false><<<dim3(8,32,3), 256, 0, stream>>>(g39);

  // 6. LN1: h = LN(proj + x) -> S(4), S(5)
  ln_fused<1,true,false><<<dim3(4096,2), 256, 0, stream>>>(
      LnJob{S(1),nullptr,nullptr, audio, F(30),F(31), S(4)},
      LnJob{S(2),nullptr,nullptr, video, F(46),F(47), S(5)});

  // 7. G5: relu(h@w1+c1) -> S(6), S(7)
  GemmJobs g5{};
  g5.A[0]=S(4); g5.W[0]=WP(4);  g5.bias[0]=F(27); g5.C[0]=S(6); g5.mode[0]=0;
  g5.A[1]=S(5); g5.W[1]=WP(10); g5.bias[1]=F(43); g5.C[1]=S(7); g5.mode[1]=0;
  gemm_n64<true><<<dim3(8,32,2), 256, 0, stream>>>(g5);

  // 8. G6: @w2+c2 -> S(8), S(9)
  GemmJobs g6{};
  g6.A[0]=S(6); g6.W[0]=WP(5);  g6.bias[0]=F(29); g6.C[0]=S(8); g6.mode[0]=0;
  g6.A[1]=S(7); g6.W[1]=WP(11); g6.bias[1]=F(45); g6.C[1]=S(9); g6.mode[1]=0;
  gemm_n64<false><<<dim3(8,32,2), 256, 0, stream>>>(g6);

  // 9. fused LN2(a) + LN2(v) + final LN -> d_out (f32)
  ln_final<<<4096, 256, 0, stream>>>(S(8),S(4), S(9),S(5), S(3), audio,
                                     F(32),F(33), F(48),F(49), F(16),F(17),
                                     (float*)d_out);
}

// Round 20
// 173.661 us; speedup vs baseline: 1.0166x; 1.0166x over previous
//
#include <hip/hip_runtime.h>
#include <cstddef>
#include <cstdint>

// B=4, S=1024, D=512, H=8, DK=64, DFF=512, M=4096. SCALE=0.125.
// Fixed-max softmax (scores ~ +-2): associative exp-sum, no online-max.
// Q projections pre-scaled by 0.125*log2(e) => v_exp_f32 (2^x) per score.
// r20 = exact r18 restore (best measured: 173.7 us). r19's enc k-split
// regressed (enc wasn't grid-starved; combine overhead uncompensated).
// attn_enc: 8 waves x 16 q full-k (r17 body). attn_dual: k-split (r18).

typedef __attribute__((ext_vector_type(8))) short s8v;   // 8 x bf16
typedef __attribute__((ext_vector_type(4))) short s4v;   // 4 x bf16
typedef __attribute__((ext_vector_type(4))) float f4v;   // MFMA acc

#define QSC 0.1803368801111444f   // 0.125 * log2(e)
#define EXP2(x) __builtin_amdgcn_exp2f(x)
#define WAITV(N) asm volatile("s_waitcnt vmcnt(" #N ")" ::: "memory")
#define BAR() __builtin_amdgcn_s_barrier()
#define PRIO(n) __builtin_amdgcn_s_setprio(n)

static __device__ __forceinline__ short f2bf(float f){
  unsigned int u = __builtin_bit_cast(unsigned int, f);
  u += 0x7fffu + ((u >> 16) & 1u);          // RNE
  return (short)(u >> 16);
}
static __device__ __forceinline__ float bf2f(short s){
  unsigned int u = ((unsigned int)(unsigned short)s) << 16;
  return __builtin_bit_cast(float, u);
}
static __device__ __forceinline__ void gload16(const void* g, void* l){
  __builtin_amdgcn_global_load_lds(
      (const __attribute__((address_space(1))) unsigned int*)g,
      (__attribute__((address_space(3))) unsigned int*)l, 16, 0, 0);
}
#define MFMA16(a,b,c) __builtin_amdgcn_mfma_f32_16x16x32_bf16(a,b,c,0,0,0)

// ---------------------------------------------------------------------------
// Fused input-convert + weight-pack.
// ---------------------------------------------------------------------------
struct Ptr19 { const float* p[19]; };

__global__ __launch_bounds__(256) void prep(const float* __restrict__ a,
                                            const float* __restrict__ v,
                                            short* __restrict__ oa,
                                            short* __restrict__ ov,
                                            Ptr19 ws, short* __restrict__ wp){
  const int b = blockIdx.x, tid = threadIdx.x;
  if (b < 2048){
    const float* src = (b >= 1024) ? v : a;
    short* dst = (b >= 1024) ? ov : oa;
    const int i = ((b & 1023) * 256 + tid) * 8;
    float4 x = *reinterpret_cast<const float4*>(src + i);
    float4 y = *reinterpret_cast<const float4*>(src + i + 4);
    s8v o;
    o[0]=f2bf(x.x); o[1]=f2bf(x.y); o[2]=f2bf(x.z); o[3]=f2bf(x.w);
    o[4]=f2bf(y.x); o[5]=f2bf(y.y); o[6]=f2bf(y.z); o[7]=f2bf(y.w);
    *reinterpret_cast<s8v*>(dst + i) = o;
  } else {
    const int pb = b - 2048;
    const int mat = pb >> 7;
    const float* W = ws.p[mat];
    const int f = (pb & 127) * 256 + tid;   // 0..32767
    const int nblk = f >> 10, kg = (f >> 4) & 63, nl = f & 15;
    const int n = nblk * 16 + nl, k = kg * 8;
    s8v o;
#pragma unroll
    for (int e = 0; e < 8; ++e) o[e] = f2bf(W[(size_t)(k + e) * 512 + n]);
    *reinterpret_cast<s8v*>(wp + (size_t)mat * 262144 + (size_t)f * 8) = o;
  }
}

// ---------------------------------------------------------------------------
// G1 GEMM: 128x256 tile, 4 waves x (64x128), acc[4][8]. 3-buffer, 1 barrier
// per K-step, vmcnt(6). mode: 0 plain, 1 QSC, 2 packed-V.
// ---------------------------------------------------------------------------
struct GemmJobs { const short* A[12]; const short* W[12]; const float* bias[12];
                  short* C[12]; int mode[12]; };

__global__ __launch_bounds__(256, 2) void gemm_wide(GemmJobs J){
  int i = (blockIdx.z * 32 + blockIdx.y) * 2 + blockIdx.x;
  const int c = (64 * gridDim.z) >> 3;
  i = (i & 7) * c + (i >> 3);
  const int z = i >> 6, rem = i & 63;
  const int by = rem >> 1, bx = rem & 1;

  const short* __restrict__ A = J.A[z];
  const short* __restrict__ Wp = J.W[z];
  const float* __restrict__ bias = J.bias[z];
  short* __restrict__ C = J.C[z];
  const int md = J.mode[z];
  __shared__ short smem[36864];                 // 72 KB arena
  const int tid = threadIdx.x, lane = tid & 63, w = tid >> 6;
  const int wm = w >> 1, wn = w & 1;
  const int m0 = by * 128, n0 = bx * 256;
  const int lh = lane >> 4, ll = lane & 15;
  f4v acc[4][8] = {};

  auto stage = [&](int kt, int buf){
    const int k0 = kt * 32;
    short* As = smem + buf * 4096;
    short* Bs = smem + 12288 + buf * 8192;
#pragma unroll
    for (int p = 0; p < 2; ++p){
      const int f = tid + 256 * p;
      const int blk = f >> 6, kg = (f >> 4) & 3, il = f & 15;
      gload16(A + (size_t)(m0 + blk * 16 + il) * 512 + k0 + kg * 8, As + f * 8);
    }
#pragma unroll
    for (int p = 0; p < 4; ++p){
      const int f = tid + 256 * p;
      const int cblk = f >> 6, kg = (f >> 4) & 3, il = f & 15;
      gload16(Wp + ((size_t)(((n0 >> 4) + cblk) * 64 + (k0 >> 3) + kg) * 16 + il) * 8,
              Bs + f * 8);
    }
  };

  stage(0, 0);
  stage(1, 1);
#pragma unroll 1
  for (int kt = 0; kt < 16; ++kt){
    if (kt < 15) { WAITV(6); } else { WAITV(0); }
    BAR();
    if (kt < 14) stage(kt + 2, (kt + 2) % 3);
    const int cur = kt % 3;
    const short* As = smem + cur * 4096;
    const short* Bs = smem + 12288 + cur * 8192;
    s8v a[4], b[8];
#pragma unroll
    for (int q = 0; q < 4; ++q)
      a[q] = *reinterpret_cast<const s8v*>(&As[(((wm*4+q)*4 + lh)*16 + ll) * 8]);
#pragma unroll
    for (int j = 0; j < 8; ++j)
      b[j] = *reinterpret_cast<const s8v*>(&Bs[(((wn*8+j)*4 + lh)*16 + ll) * 8]);
    PRIO(1);
#pragma unroll
    for (int q = 0; q < 4; ++q)
#pragma unroll
      for (int j = 0; j < 8; ++j)
        acc[q][j] = MFMA16(a[q], b[j], acc[q][j]);
    PRIO(0);
  }
  BAR();                          // epilogue reuses arena

  if (md == 2){
#pragma unroll
    for (int j = 0; j < 8; ++j){
      const int col = n0 + wn * 128 + j * 16 + ll;
      const float bv = bias[col];
      const int hh = col >> 6, dl = col & 63, dblk = dl >> 4, il = dl & 15;
#pragma unroll
      for (int q = 0; q < 4; ++q){
        const int rowb = m0 + wm * 64 + q * 16 + lh * 4;
        const int bb = rowb >> 10, srow = rowb & 1023;
        const size_t off = ((size_t)((bb*8 + hh)*16 + (srow >> 6))) * 4096
                         + (size_t)(((dblk << 7) + (((srow >> 3) & 7) << 4) + il) * 8 + (srow & 7));
        s4v o4;
#pragma unroll
        for (int r = 0; r < 4; ++r) o4[r] = f2bf(acc[q][j][r] + bv);
        *reinterpret_cast<s4v*>(&C[off]) = o4;
      }
    }
  } else {
    short* epi = smem + w * 8192;
    const float sc = (md == 1) ? QSC : 1.0f;
#pragma unroll
    for (int j = 0; j < 8; ++j){
      const float bv = bias[n0 + wn * 128 + j * 16 + ll];
#pragma unroll
      for (int q = 0; q < 4; ++q)
#pragma unroll
        for (int r = 0; r < 4; ++r)
          epi[(q*16 + lh*4 + r)*128 + j*16 + ll] = f2bf((acc[q][j][r] + bv) * sc);
    }
#pragma unroll
    for (int i2 = 0; i2 < 16; ++i2){
      const int row = i2 * 4 + (lane >> 4);
      s8v vr = *reinterpret_cast<const s8v*>(&epi[row*128 + (lane & 15)*8]);
      *reinterpret_cast<s8v*>(&C[(size_t)(m0 + wm*64 + row)*512 + n0 + wn*128 + (lane&15)*8]) = vr;
    }
  }
}

// ---------------------------------------------------------------------------
// bf16 MFMA GEMM, 128x64 tile (small launches). 3-buffer, 1 barrier/K-step.
// ---------------------------------------------------------------------------
template<bool RELU>
__global__ __launch_bounds__(256) void gemm_n64(GemmJobs J){
  int i = (blockIdx.z * 32 + blockIdx.y) * 8 + blockIdx.x;
  const int c = (256 * gridDim.z) >> 3;
  i = (i & 7) * c + (i >> 3);
  const int z = i >> 8, rem = i & 255;
  const int by = rem >> 3, bx = rem & 7;

  const short* __restrict__ A = J.A[z];
  const short* __restrict__ Wp = J.W[z];
  const float* __restrict__ bias = J.bias[z];
  short* __restrict__ C = J.C[z];
  __shared__ short As[3][4096], Bs[3][2048];   // 36 KB
  const int tid = threadIdx.x, lane = tid & 63, w = tid >> 6;
  const int wm = w >> 1, wn = w & 1;
  const int m0 = by * 128, n0 = bx * 64;
  const int lh = lane >> 4, ll = lane & 15;
  f4v acc[4][2] = {};

  auto stage = [&](int kt, int buf){
    const int k0 = kt * 32;
#pragma unroll
    for (int p = 0; p < 2; ++p){
      const int f = tid + 256 * p;
      const int blk = f >> 6, kg = (f >> 4) & 3, il = f & 15;
      gload16(A + (size_t)(m0 + blk * 16 + il) * 512 + k0 + kg * 8, &As[buf][f * 8]);
    }
    {
      const int f = tid;
      const int blk = f >> 6, kg = (f >> 4) & 3, il = f & 15;
      gload16(Wp + ((size_t)(((n0 >> 4) + blk) * 64 + (k0 >> 3) + kg) * 16 + il) * 8,
              &Bs[buf][f * 8]);
    }
  };

  stage(0, 0);
  stage(1, 1);
#pragma unroll 1
  for (int kt = 0; kt < 16; ++kt){
    if (kt < 15) { WAITV(3); } else { WAITV(0); }
    BAR();
    if (kt < 14) stage(kt + 2, (kt + 2) % 3);
    const int cur = kt % 3;
    s8v a[4], b[2];
#pragma unroll
    for (int q = 0; q < 4; ++q)
      a[q] = *reinterpret_cast<const s8v*>(&As[cur][(((wm*4+q)*4 + lh)*16 + ll) * 8]);
#pragma unroll
    for (int j = 0; j < 2; ++j)
      b[j] = *reinterpret_cast<const s8v*>(&Bs[cur][(((wn*2+j)*4 + lh)*16 + ll) * 8]);
    PRIO(1);
#pragma unroll
    for (int q = 0; q < 4; ++q)
#pragma unroll
      for (int j = 0; j < 2; ++j)
        acc[q][j] = MFMA16(a[q], b[j], acc[q][j]);
    PRIO(0);
  }
  BAR();

  short* epi = &As[0][0] + w * 2048;
#pragma unroll
  for (int j = 0; j < 2; ++j){
    const float bv = bias[n0 + wn * 32 + j * 16 + ll];
#pragma unroll
    for (int q = 0; q < 4; ++q)
#pragma unroll
      for (int r = 0; r < 4; ++r){
        float v = acc[q][j][r] + bv;
        if (RELU) v = fmaxf(v, 0.f);
        epi[(q*16 + lh*4 + r)*32 + j*16 + ll] = f2bf(v);
      }
  }
#pragma unroll
  for (int i2 = 0; i2 < 4; ++i2){
    const int row = i2 * 16 + (lane >> 2);
    s8v vr = *reinterpret_cast<const s8v*>(&epi[row*32 + (lane & 3)*8]);
    *reinterpret_cast<s8v*>(&C[(size_t)(m0 + wm*64 + row)*512 + n0 + wn*32 + (lane&3)*8]) = vr;
  }
}

// ---------------------------------------------------------------------------
// Encoder self-attention, swapped QK^T. 8 waves x 16 q = 128 q/block.
// P^T in LDS: 4x ds_write_b64; PV: O^T = mfma(V^T, P^T); O: 4x short4.
// ---------------------------------------------------------------------------
struct AttnJob { const short* Q; const short* K; const short* Vp; short* O; };

__global__ __launch_bounds__(512) void attn_enc(AttnJob j0, AttnJob j1){
  const AttnJob jb = blockIdx.z ? j1 : j0;
  __shared__ short KT[2][4096], VT[2][4096];   // 32 KB
  __shared__ short PL[8][1024];                // 16 KB
  const int tid = threadIdx.x, lane = tid & 63, w = tid >> 6;  // w 0..7
  int bi = blockIdx.y * 8 + blockIdx.x;
  bi = (bi & 7) * 32 + (bi >> 3);              // bijective XCD swizzle
  const int qt = bi & 7, bh = bi >> 3;
  const int b = bh >> 3, h = bh & 7;
  const int q0 = qt * 128;
  const size_t base = (size_t)b * 1024 * 512 + (size_t)h * 64;
  const int lh = lane >> 4, ll = lane & 15;
  short* PLw = PL[w];

  s8v qf[2];
#pragma unroll
  for (int df = 0; df < 2; ++df)
    qf[df] = *reinterpret_cast<const s8v*>(jb.Q + base + (size_t)(q0 + w*16 + ll)*512 + lh*8 + df*32);

  const int sblk = tid >> 7, sg8 = (tid >> 4) & 7, sil = tid & 15;
  auto stage = [&](int it, int buf){
    gload16(jb.K + base + (size_t)(it*64 + sblk*16 + sil)*512 + sg8*8, &KT[buf][tid*8]);
    gload16(jb.Vp + ((size_t)bh*16 + it)*4096 + (size_t)tid*8, &VT[buf][tid*8]);
  };

  f4v o[4] = {};
  float zacc = 0.f;
  const int pwo = ((lh >> 1) * 16 + ll) * 8 + (lh & 1) * 4;   // P^T write offset
  const int pro = ((lh) * 16 + ll) * 8;                       // P^T read base

  stage(0, 0);
#pragma unroll 1
  for (int it = 0; it < 16; ++it){
    if (it < 15) { stage(it + 1, (it + 1) & 1); WAITV(2); }
    else         { WAITV(0); }
    BAR();
    const int cur = it & 1;

    f4v s[4] = {};
    PRIO(1);
#pragma unroll
    for (int fn = 0; fn < 4; ++fn)
#pragma unroll
      for (int df = 0; df < 2; ++df){
        s8v kf = *reinterpret_cast<const s8v*>(&KT[cur][((fn*8 + lh + df*4)*16 + ll) * 8]);
        s[fn] = MFMA16(kf, qf[df], s[fn]);    // P^T: row=k, col=q
      }
    PRIO(0);

#pragma unroll
    for (int fn = 0; fn < 4; ++fn){
      s4v p4;
#pragma unroll
      for (int r = 0; r < 4; ++r){
        const float p = EXP2(s[fn][r]);
        zacc += p;
        p4[r] = f2bf(p);
      }
      *reinterpret_cast<s4v*>(&PLw[fn*256 + pwo]) = p4;
    }
    s8v pa[2];
#pragma unroll
    for (int kf2 = 0; kf2 < 2; ++kf2)
      pa[kf2] = *reinterpret_cast<const s8v*>(&PLw[kf2*512 + pro]);
    PRIO(1);
#pragma unroll
    for (int fd = 0; fd < 4; ++fd)
#pragma unroll
      for (int kf2 = 0; kf2 < 2; ++kf2){
        s8v vf = *reinterpret_cast<const s8v*>(&VT[cur][((fd*8 + lh + kf2*4)*16 + ll) * 8]);
        o[fd] = MFMA16(vf, pa[kf2], o[fd]);   // O^T: row=d, col=q
      }
    PRIO(0);
    BAR();
  }

  float Z = zacc;
  Z += __shfl_xor(Z, 16); Z += __shfl_xor(Z, 32);
  const float rz = 1.f / Z;
#pragma unroll
  for (int fd = 0; fd < 4; ++fd){
    s4v o4;
#pragma unroll
    for (int r = 0; r < 4; ++r) o4[r] = f2bf(o[fd][r] * rz);
    *reinterpret_cast<s4v*>(&jb.O[base + (size_t)(q0 + w*16 + ll)*512 + fd*16 + lh*4]) = o4;
  }
}

// ---------------------------------------------------------------------------
// Dual-softmax cross attention, swapped QK^T, k-split. 8 waves = 4 q-waves
// (16 q each, 64 q/block) x 2 k-halves; KVBLK=32; each wave stages its own
// half. 512 blocks -> 2 blocks/CU = 16 waves/CU.
// ---------------------------------------------------------------------------
__global__ __launch_bounds__(512) void attn_dual(const short* __restrict__ Qa, const short* __restrict__ Ka,
                                                 const short* __restrict__ Vap, const short* __restrict__ Qv,
                                                 const short* __restrict__ Kv, const short* __restrict__ Vvp,
                                                 short* __restrict__ O){
  __shared__ short smem[36864];                // 72 KB
  const int tid = threadIdx.x, lane = tid & 63, w = tid >> 6;
  const int qw = w & 3, kh = w >> 2;
  int bi = blockIdx.y * 16 + blockIdx.x;       // 512 blocks
  bi = (bi & 7) * 64 + (bi >> 3);              // bijective XCD swizzle
  const int qt = bi & 15, bh = bi >> 4;
  const int b = bh >> 3, h = bh & 7;
  const int q0 = qt * 64;
  const size_t base = (size_t)b * 1024 * 512 + (size_t)h * 64;
  const int lh = lane >> 4, ll = lane & 15;
  short* PLw = smem + 32768 + w * 512;

  s8v qfa[2], qfv[2];
#pragma unroll
  for (int df = 0; df < 2; ++df){
    const size_t ro = base + (size_t)(q0 + qw*16 + ll)*512 + lh*8 + df*32;
    qfa[df] = *reinterpret_cast<const s8v*>(Qa + ro);
    qfv[df] = *reinterpret_cast<const s8v*>(Qv + ro);
  }

  const int hh = tid >> 8;                     // == kh (wave stages its half)
  const int u = tid & 255;
  const int kblk = u >> 7, kg8 = (u >> 4) & 7, kil = u & 15;   // K unit coords
  const int vdb = u >> 6, vk4 = (u >> 4) & 3,  vil = u & 15;   // V unit coords

  auto stage = [&](int it, int buf){
    const int dso = hh * 4096 + buf * 2048 + u * 8;
    const size_t krow = base + (size_t)(hh*512 + it*32 + kblk*16 + kil)*512 + kg8*8;
    gload16(Ka + krow, smem + dso);
    gload16(Kv + krow, smem + 8192 + dso);
    const int kt16 = hh*8 + (it >> 1);
    const int kgrp = (it & 1)*4 + vk4;
    const size_t voff = ((size_t)bh*16 + kt16)*4096 + (size_t)((vdb*8 + kgrp)*16 + vil)*8;
    gload16(Vap + voff, smem + 16384 + dso);
    gload16(Vvp + voff, smem + 24576 + dso);
  };

  f4v oa[4] = {}, ov[4] = {};
  float za = 0.f, zv = 0.f;
  const int pwo = ((lh >> 1) * 16 + ll) * 8 + (lh & 1) * 4;   // P^T write
  const int pro = (lh * 16 + ll) * 8;                         // P^T read

  stage(0, 0);
#pragma unroll 1
  for (int it = 0; it < 16; ++it){
    if (it < 15) { stage(it + 1, (it + 1) & 1); WAITV(4); }
    else         { WAITV(0); }
    BAR();
    const int cur = it & 1;
    const int to = kh * 4096 + cur * 2048;
    const short* pKa = smem + to;
    const short* pKv = smem + 8192 + to;
    const short* pVa = smem + 16384 + to;
    const short* pVv = smem + 24576 + to;

    f4v sa[2] = {}, sv[2] = {};
    PRIO(1);
#pragma unroll
    for (int fn = 0; fn < 2; ++fn)
#pragma unroll
      for (int df = 0; df < 2; ++df){
        const int boff = (fn*128 + (lh + df*4)*16 + ll) * 8;
        s8v ka = *reinterpret_cast<const s8v*>(&pKa[boff]);
        s8v kv = *reinterpret_cast<const s8v*>(&pKv[boff]);
        sa[fn] = MFMA16(ka, qfa[df], sa[fn]);
        sv[fn] = MFMA16(kv, qfv[df], sv[fn]);
      }
    PRIO(0);

#pragma unroll
    for (int fn = 0; fn < 2; ++fn){
      s4v p4;
#pragma unroll
      for (int r = 0; r < 4; ++r){
        const float ea = EXP2(sa[fn][r]);
        const float ev = EXP2(sv[fn][r]);
        za += ea; zv += ev;
        p4[r] = f2bf(ea * ev);
      }
      *reinterpret_cast<s4v*>(&PLw[fn*256 + pwo]) = p4;
    }
    s8v pa = *reinterpret_cast<const s8v*>(&PLw[pro]);
    PRIO(1);
#pragma unroll
    for (int fd = 0; fd < 4; ++fd){
      const int voff2 = (fd*64 + lh*16 + ll) * 8;
      s8v va = *reinterpret_cast<const s8v*>(&pVa[voff2]);
      s8v vv = *reinterpret_cast<const s8v*>(&pVv[voff2]);
      oa[fd] = MFMA16(va, pa, oa[fd]);
      ov[fd] = MFMA16(vv, pa, ov[fd]);
    }
    PRIO(0);
    BAR();
  }

  // combine k-halves: kh=1 writes partials; kh=0 accumulates + finalizes
  float* cb = (float*)smem;                    // 34 KB of the 72 KB arena
  const int idx = qw * 64 + lane;              // 0..255
  if (kh == 1){
#pragma unroll
    for (int fd = 0; fd < 4; ++fd)
#pragma unroll
      for (int r = 0; r < 4; ++r){
        cb[(fd*4 + r)*256 + idx] = oa[fd][r];
        cb[(16 + fd*4 + r)*256 + idx] = ov[fd][r];
      }
    cb[32*256 + idx] = za;
    cb[33*256 + idx] = zv;
  }
  BAR();
  if (kh == 0){
#pragma unroll
    for (int fd = 0; fd < 4; ++fd)
#pragma unroll
      for (int r = 0; r < 4; ++r){
        oa[fd][r] += cb[(fd*4 + r)*256 + idx];
        ov[fd][r] += cb[(16 + fd*4 + r)*256 + idx];
      }
    float Za = za + cb[32*256 + idx];
    float Zv = zv + cb[33*256 + idx];
    Za += __shfl_xor(Za, 16); Za += __shfl_xor(Za, 32);
    Zv += __shfl_xor(Zv, 16); Zv += __shfl_xor(Zv, 32);
    const float rz = 1.f / (Za * Zv);
#pragma unroll
    for (int fd = 0; fd < 4; ++fd){
      s4v o4;
#pragma unroll
      for (int r = 0; r < 4; ++r){
        const float v = (oa[fd][r] * rz) * (ov[fd][r] * rz);
        o4[r] = f2bf(v);
      }
      *reinterpret_cast<s4v*>(&O[base + (size_t)(q0 + qw*16 + ll)*512 + fd*16 + lh*4]) = o4;
    }
  }
}

// ---------------------------------------------------------------------------
struct LnJob { const short* xb0; const short* xb1; const short* xb2;
               const float* xf; const float* g; const float* bb; void* out; };

template<int NBF, bool ADDF32, bool OUTF32>
__global__ __launch_bounds__(256) void ln_fused(LnJob j0, LnJob j1){
  const LnJob j = blockIdx.y ? j1 : j0;
  const int row = blockIdx.x, t = threadIdx.x;
  const size_t base = (size_t)row * 512;
  float x[2];
#pragma unroll
  for (int u = 0; u < 2; ++u){
    const int c = t + u * 256;
    float v = bf2f(j.xb0[base + c]);
    if (NBF > 1) v += bf2f(j.xb1[base + c]);
    if (NBF > 2) v += bf2f(j.xb2[base + c]);
    if (ADDF32) v += j.xf[base + c];
    x[u] = v;
  }
  float s = x[0] + x[1], ss = x[0]*x[0] + x[1]*x[1];
#pragma unroll
  for (int o = 32; o; o >>= 1){ s += __shfl_xor(s, o); ss += __shfl_xor(ss, o); }
  __shared__ float rb[8];
  const int wv = t >> 6;
  if ((t & 63) == 0){ rb[wv] = s; rb[wv + 4] = ss; }
  __syncthreads();
  s  = rb[0] + rb[1] + rb[2] + rb[3];
  ss = rb[4] + rb[5] + rb[6] + rb[7];
  const float m = s * (1.f / 512.f);
  const float var = ss * (1.f / 512.f) - m * m;
  const float rstd = rsqrtf(var + 1e-5f);
#pragma unroll
  for (int u = 0; u < 2; ++u){
    const int c = t + u * 256;
    const float v = (x[u] - m) * rstd * j.g[c] + j.bb[c];
    if (OUTF32) ((float*)j.out)[base + c] = v;
    else        ((short*)j.out)[base + c] = f2bf(v);
  }
}

// ---------------------------------------------------------------------------
// Fused LN2(audio) + LN2(video) + final LN.
// ---------------------------------------------------------------------------
__global__ __launch_bounds__(256) void ln_final(const short* __restrict__ fa, const short* __restrict__ ha,
                                                const short* __restrict__ fv, const short* __restrict__ hv,
                                                const short* __restrict__ ctx, const float* __restrict__ audio,
                                                const float* __restrict__ g2a, const float* __restrict__ b2a,
                                                const float* __restrict__ g2v, const float* __restrict__ b2v,
                                                const float* __restrict__ gf, const float* __restrict__ bf,
                                                float* __restrict__ out){
  const int row = blockIdx.x, t = threadIdx.x;
  const size_t base = (size_t)row * 512;
  __shared__ float rb[24];
  const int wv = t >> 6;

  auto reduce2 = [&](float a, float b, int p){
    float s = a + b, ss = a*a + b*b;
#pragma unroll
    for (int o = 32; o; o >>= 1){ s += __shfl_xor(s, o); ss += __shfl_xor(ss, o); }
    if ((t & 63) == 0){ rb[p*8 + wv] = s; rb[p*8 + 4 + wv] = ss; }
  };
  auto stats = [&](int p, float& m, float& rstd){
    const float s  = rb[p*8+0] + rb[p*8+1] + rb[p*8+2] + rb[p*8+3];
    const float ss = rb[p*8+4] + rb[p*8+5] + rb[p*8+6] + rb[p*8+7];
    m = s * (1.f / 512.f);
    rstd = rsqrtf(ss * (1.f / 512.f) - m * m + 1e-5f);
  };

  float xa[2], xv[2];
#pragma unroll
  for (int u = 0; u < 2; ++u){
    const int c = t + u * 256;
    xa[u] = bf2f(fa[base + c]) + bf2f(ha[base + c]);
    xv[u] = bf2f(fv[base + c]) + bf2f(hv[base + c]);
  }
  reduce2(xa[0], xa[1], 0);
  reduce2(xv[0], xv[1], 1);
  __syncthreads();
  float ma, ra, mv, rv;
  stats(0, ma, ra);
  stats(1, mv, rv);

  float xf[2];
#pragma unroll
  for (int u = 0; u < 2; ++u){
    const int c = t + u * 256;
    const float sa = (xa[u] - ma) * ra * g2a[c] + b2a[c];
    const float sv = (xv[u] - mv) * rv * g2v[c] + b2v[c];
    xf[u] = audio[base + c] + bf2f(ctx[base + c]) + sa + sv;
  }
  reduce2(xf[0], xf[1], 2);
  __syncthreads();
  float mf, rf;
  stats(2, mf, rf);
#pragma unroll
  for (int u = 0; u < 2; ++u){
    const int c = t + u * 256;
    out[base + c] = (xf[u] - mf) * rf * gf[c] + bf[c];
  }
}

// ---------------------------------------------------------------------------
extern "C" void kernel_launch(void* const* d_in, const int* in_sizes, int n_in,
                              void* d_out, int out_size, void* d_ws, size_t ws_size,
                              hipStream_t stream) {
  const float* audio = (const float*)d_in[0];
  const float* video = (const float*)d_in[1];
  auto F = [&](int i){ return (const float*)d_in[i]; };

  short* ws16 = (short*)d_ws;
  const size_t SL = 2097152;                       // shorts per 4MB slot
  auto S = [&](int i){ return ws16 + (size_t)i * SL; };
  short* Wp = S(12);                               // 19 * 262144 shorts
  auto WP = [&](int i){ return (const short*)(Wp + (size_t)i * 262144); };
  short* Kcv = (short*)d_out;                      // d_out as bf16 scratch
  short* Vcv = (short*)d_out + SL;

  // 1. fused: inputs -> bf16 + pack 19 weights
  Ptr19 pw;
  const int widx[19] = {18,19,20,21,26,28, 34,35,36,37,42,44, 2,4,6,8,10,12, 14};
  for (int i = 0; i < 19; ++i) pw.p[i] = F(widx[i]);
  prep<<<4480, 256, 0, stream>>>(audio, video, S(10), S(11), pw, Wp);

  // 2. G1: all 12 QKV projections (wide tile); Q scaled, V packed
  GemmJobs g1{};
  const short* g1A[12] = {S(10),S(10),S(10), S(11),S(11),S(11), S(10),S(10),S(10), S(11),S(11),S(11)};
  const short* g1W[12] = {WP(0),WP(1),WP(2), WP(6),WP(7),WP(8), WP(12),WP(13),WP(14), WP(15),WP(16),WP(17)};
  const float* g1B[12] = {F(22),F(23),F(24), F(38),F(39),F(40), F(3),F(5),F(7), F(9),F(11),F(13)};
  short*       g1C[12] = {S(0),S(1),S(2), S(3),S(4),S(5), S(6),S(7),S(8), S(9),Kcv,Vcv};
  const int    g1M[12] = {1,0,2, 1,0,2, 1,0,2, 1,0,2};
  for (int i = 0; i < 12; ++i){ g1.A[i]=g1A[i]; g1.W[i]=g1W[i]; g1.bias[i]=g1B[i]; g1.C[i]=g1C[i]; g1.mode[i]=g1M[i]; }
  gemm_wide<<<dim3(2,32,12), 256, 0, stream>>>(g1);

  // 3. encoder self-attention (audio + video): ctx -> S(10), S(11)
  attn_enc<<<dim3(8,32,2), 512, 0, stream>>>(AttnJob{S(0),S(1),S(2),S(10)},
                                             AttnJob{S(3),S(4),S(5),S(11)});

  // 4. dual cross-attention (k-split, 512 blocks) -> S(0)
  attn_dual<<<dim3(16,32), 512, 0, stream>>>(S(6),S(7),S(8), S(9),Kcv,Vcv, S(0));

  // 5. G3+G9 merged: ctxA@ow->S(1), ctxV@ow->S(2), ctxD@out_w->S(3)
  GemmJobs g39{};
  g39.A[0]=S(10); g39.W[0]=WP(3);  g39.bias[0]=F(25); g39.C[0]=S(1); g39.mode[0]=0;
  g39.A[1]=S(11); g39.W[1]=WP(9);  g39.bias[1]=F(41); g39.C[1]=S(2); g39.mode[1]=0;
  g39.A[2]=S(0);  g39.W[2]=WP(18); g39.bias[2]=F(15); g39.C[2]=S(3); g39.mode[2]=0;
  gemm_n64<false><<<dim3(8,32,3), 256, 0, stream>>>(g39);

  // 6. LN1: h = LN(proj + x) -> S(4), S(5)
  ln_fused<1,true,false><<<dim3(4096,2), 256, 0, stream>>>(
      LnJob{S(1),nullptr,nullptr, audio, F(30),F(31), S(4)},
      LnJob{S(2),nullptr,nullptr, video, F(46),F(47), S(5)});

  // 7. G5: relu(h@w1+c1) -> S(6), S(7)
  GemmJobs g5{};
  g5.A[0]=S(4); g5.W[0]=WP(4);  g5.bias[0]=F(27); g5.C[0]=S(6); g5.mode[0]=0;
  g5.A[1]=S(5); g5.W[1]=WP(10); g5.bias[1]=F(43); g5.C[1]=S(7); g5.mode[1]=0;
  gemm_n64<true><<<dim3(8,32,2), 256, 0, stream>>>(g5);

  // 8. G6: @w2+c2 -> S(8), S(9)
  GemmJobs g6{};
  g6.A[0]=S(6); g6.W[0]=WP(5);  g6.bias[0]=F(29); g6.C[0]=S(8); g6.mode[0]=0;
  g6.A[1]=S(7); g6.W[1]=WP(11); g6.bias[1]=F(45); g6.C[1]=S(9); g6.mode[1]=0;
  gemm_n64<false><<<dim3(8,32,2), 256, 0, stream>>>(g6);

  // 9. fused LN2(a) + LN2(v) + final LN -> d_out (f32)
  ln_final<<<4096, 256, 0, stream>>>(S(8),S(4), S(9),S(5), S(3), audio,
                                     F(32),F(33), F(48),F(49), F(16),F(17),
                                     (float*)d_out);
}